// Round 1
// baseline (26840.771 us; speedup 1.0000x reference)
//
#include <hip/hip_runtime.h>
#include <hip/hip_bf16.h>

#define B_ 64
#define T_ 512
#define D_ 512
#define H_ 1024
#define LN_EPS 1e-3f

// ---------------------------------------------------------------------------
// GEMM1: out[m,n] = sum_k X[m,k]*W[k,n] + bias[n]    (M=B*T=32768, K=512, N=1024)
// 64x64 tile, BK=16, 256 threads, 4x4 thread tile. fp32 (correctness anchor).
// ---------------------------------------------------------------------------
__global__ __launch_bounds__(256) void gemm1_kernel(
    const float* __restrict__ X, const float* __restrict__ W,
    const float* __restrict__ bias, float* __restrict__ out)
{
    __shared__ float sA[16][64];  // [k][m]
    __shared__ float sB[16][64];  // [k][n]
    const int m0 = blockIdx.x * 64;
    const int n0 = blockIdx.y * 64;
    const int t  = threadIdx.x;
    const int tx = t & 15, ty = t >> 4;

    const int ar = t >> 2, ak = (t & 3) * 4;   // A tile: 64 rows x 16 k
    const int bk = t >> 4, bc = (t & 15) * 4;  // B tile: 16 k x 64 cols

    float acc[4][4] = {};

    for (int k0 = 0; k0 < D_; k0 += 16) {
        float4 av = *(const float4*)(X + (size_t)(m0 + ar) * D_ + k0 + ak);
        float4 bv = *(const float4*)(W + (size_t)(k0 + bk) * H_ + n0 + bc);
        __syncthreads();  // protect previous iteration's LDS reads
        sA[ak + 0][ar] = av.x;
        sA[ak + 1][ar] = av.y;
        sA[ak + 2][ar] = av.z;
        sA[ak + 3][ar] = av.w;
        *(float4*)&sB[bk][bc] = bv;
        __syncthreads();
#pragma unroll
        for (int kk = 0; kk < 16; ++kk) {
            float4 a = *(const float4*)&sA[kk][ty * 4];
            float4 b = *(const float4*)&sB[kk][tx * 4];
            acc[0][0] += a.x * b.x; acc[0][1] += a.x * b.y; acc[0][2] += a.x * b.z; acc[0][3] += a.x * b.w;
            acc[1][0] += a.y * b.x; acc[1][1] += a.y * b.y; acc[1][2] += a.y * b.z; acc[1][3] += a.y * b.w;
            acc[2][0] += a.z * b.x; acc[2][1] += a.z * b.y; acc[2][2] += a.z * b.z; acc[2][3] += a.z * b.w;
            acc[3][0] += a.w * b.x; acc[3][1] += a.w * b.y; acc[3][2] += a.w * b.z; acc[3][3] += a.w * b.w;
        }
    }

#pragma unroll
    for (int i = 0; i < 4; ++i) {
        const int row = m0 + ty * 4 + i;
        const int col = n0 + tx * 4;
        float4 bv = *(const float4*)(bias + col);
        float4 o;
        o.x = acc[i][0] + bv.x;
        o.y = acc[i][1] + bv.y;
        o.z = acc[i][2] + bv.z;
        o.w = acc[i][3] + bv.w;
        *(float4*)(out + (size_t)row * H_ + col) = o;
    }
}

// ---------------------------------------------------------------------------
// Per-step matmul: z[b,c] = xw[b,t,c] + sum_k h[b,k] * U[k,c]
// 128 WGs x 256 threads. WG owns 8 columns; threads: 2 k-slices x (2 colgroups
// of 4 cols x 64 rows). float4 U loads (contiguous in c), float4 h loads.
// ---------------------------------------------------------------------------
__global__ __launch_bounds__(256) void step_mm_kernel(
    const float* __restrict__ hbuf, const float* __restrict__ U,
    const float* __restrict__ xw, float* __restrict__ z, int t)
{
    const int tid = threadIdx.x;
    const int c0  = blockIdx.x * 8;
    const int ks  = tid >> 7;        // k-slice 0/1 (k in [ks*512, ks*512+512))
    const int rem = tid & 127;
    const int cg  = rem & 1;         // column group (4 cols each)
    const int r   = rem >> 1;        // batch row 0..63
    const int c   = c0 + cg * 4;

    const float* hrow = hbuf + (size_t)r * H_ + ks * 512;
    const float* ucol = U + (size_t)ks * 512 * H_ + c;

    float4 acc = {0.f, 0.f, 0.f, 0.f};
#pragma unroll 4
    for (int k = 0; k < 512; k += 4) {
        float4 hv = *(const float4*)(hrow + k);
        float4 u0 = *(const float4*)(ucol + (size_t)(k + 0) * H_);
        float4 u1 = *(const float4*)(ucol + (size_t)(k + 1) * H_);
        float4 u2 = *(const float4*)(ucol + (size_t)(k + 2) * H_);
        float4 u3 = *(const float4*)(ucol + (size_t)(k + 3) * H_);
        acc.x += hv.x * u0.x + hv.y * u1.x + hv.z * u2.x + hv.w * u3.x;
        acc.y += hv.x * u0.y + hv.y * u1.y + hv.z * u2.y + hv.w * u3.y;
        acc.z += hv.x * u0.z + hv.y * u1.z + hv.z * u2.z + hv.w * u3.z;
        acc.w += hv.x * u0.w + hv.y * u1.w + hv.z * u2.w + hv.w * u3.w;
    }

    __shared__ float4 red[128];
    if (ks == 1) red[rem] = acc;
    __syncthreads();
    if (ks == 0) {
        float4 o = red[rem];
        float4 xv = *(const float4*)(xw + ((size_t)r * T_ + t) * H_ + c);
        o.x += acc.x + xv.x;
        o.y += acc.y + xv.y;
        o.z += acc.z + xv.z;
        o.w += acc.w + xv.w;
        *(float4*)(z + (size_t)r * H_ + c) = o;
    }
}

// ---------------------------------------------------------------------------
// Per-step LN + tanh: h_new[b,c] = tanh((z-mu)*rsqrt(var+eps)*gamma + beta)
// 64 WGs (one per batch row) x 256 threads (float4 each = 1024 cols).
// Writes h buffer (recurrent state) and out[b,t,:].
// ---------------------------------------------------------------------------
__global__ __launch_bounds__(256) void step_ln_kernel(
    const float* __restrict__ z, const float* __restrict__ gamma,
    const float* __restrict__ beta, float* __restrict__ hbuf,
    float* __restrict__ out, int t)
{
    const int b   = blockIdx.x;
    const int tid = threadIdx.x;
    const int c   = tid * 4;

    float4 zv = *(const float4*)(z + (size_t)b * H_ + c);
    float s = zv.x + zv.y + zv.z + zv.w;
    float q = zv.x * zv.x + zv.y * zv.y + zv.z * zv.z + zv.w * zv.w;
#pragma unroll
    for (int o = 32; o > 0; o >>= 1) {
        s += __shfl_down(s, o);
        q += __shfl_down(q, o);
    }
    __shared__ float ps[4], pq[4];
    __shared__ float smu, srstd;
    const int wid = tid >> 6, lane = tid & 63;
    if (lane == 0) { ps[wid] = s; pq[wid] = q; }
    __syncthreads();
    if (tid == 0) {
        float S = ps[0] + ps[1] + ps[2] + ps[3];
        float Q = pq[0] + pq[1] + pq[2] + pq[3];
        float mu  = S * (1.0f / H_);
        float var = Q * (1.0f / H_) - mu * mu;
        smu = mu;
        srstd = rsqrtf(var + LN_EPS);
    }
    __syncthreads();
    const float mu = smu, rstd = srstd;

    float4 g  = *(const float4*)(gamma + c);
    float4 be = *(const float4*)(beta + c);
    float4 o;
    o.x = tanhf((zv.x - mu) * rstd * g.x + be.x);
    o.y = tanhf((zv.y - mu) * rstd * g.y + be.y);
    o.z = tanhf((zv.z - mu) * rstd * g.z + be.z);
    o.w = tanhf((zv.w - mu) * rstd * g.w + be.w);

    *(float4*)(hbuf + (size_t)b * H_ + c) = o;
    *(float4*)(out + ((size_t)b * T_ + t) * H_ + c) = o;
}

// ---------------------------------------------------------------------------
extern "C" void kernel_launch(void* const* d_in, const int* in_sizes, int n_in,
                              void* d_out, int out_size, void* d_ws, size_t ws_size,
                              hipStream_t stream)
{
    const float* X     = (const float*)d_in[0];  // [B,T,D]
    const float* W     = (const float*)d_in[1];  // [D,H]
    const float* U     = (const float*)d_in[2];  // [H,H]
    const float* bias  = (const float*)d_in[3];  // [H]
    const float* gamma = (const float*)d_in[4];  // [H]
    const float* beta  = (const float*)d_in[5];  // [H]
    float* out = (float*)d_out;                  // [B,T,H]; holds xW first, then h

    float* hbuf = (float*)d_ws;                  // [B,H] fp32 recurrent state
    float* zbuf = hbuf + B_ * H_;                // [B,H] fp32 pre-LN activations

    // h0 = 0 (ws is poisoned 0xAA before every timed launch)
    hipMemsetAsync(hbuf, 0, (size_t)B_ * H_ * sizeof(float), stream);

    // xW + b  -> stored in d_out (overwritten in-place by the recurrence)
    gemm1_kernel<<<dim3(512, 16), 256, 0, stream>>>(X, W, bias, out);

    for (int t = 0; t < T_; ++t) {
        step_mm_kernel<<<128, 256, 0, stream>>>(hbuf, U, out, zbuf, t);
        step_ln_kernel<<<64, 256, 0, stream>>>(zbuf, gamma, beta, hbuf, out, t);
    }
}

// Round 2
// 13041.495 us; speedup vs baseline: 2.0581x; 2.0581x over previous
//
#include <hip/hip_runtime.h>
#include <hip/hip_bf16.h>

#define B_ 64
#define T_ 512
#define D_ 512
#define H_ 1024
#define LN_EPS 1e-3f

typedef short bf16x8 __attribute__((ext_vector_type(8)));
typedef float f32x4  __attribute__((ext_vector_type(4)));

static __device__ __forceinline__ unsigned short f32_to_bf16_rn(float x) {
    unsigned u = __float_as_uint(x);
    unsigned r = (u + 0x7fffu + ((u >> 16) & 1u)) >> 16;
    return (unsigned short)r;
}
static __device__ __forceinline__ float bf16_to_f32(unsigned short h) {
    return __uint_as_float(((unsigned)h) << 16);
}

// ---------------------------------------------------------------------------
// GEMM1 (unchanged fp32 anchor): out = X@W + b   M=32768 K=512 N=1024
// ---------------------------------------------------------------------------
__global__ __launch_bounds__(256) void gemm1_kernel(
    const float* __restrict__ X, const float* __restrict__ W,
    const float* __restrict__ bias, float* __restrict__ out)
{
    __shared__ float sA[16][64];
    __shared__ float sB[16][64];
    const int m0 = blockIdx.x * 64;
    const int n0 = blockIdx.y * 64;
    const int t  = threadIdx.x;
    const int tx = t & 15, ty = t >> 4;
    const int ar = t >> 2, ak = (t & 3) * 4;
    const int bk = t >> 4, bc = (t & 15) * 4;

    float acc[4][4] = {};
    for (int k0 = 0; k0 < D_; k0 += 16) {
        float4 av = *(const float4*)(X + (size_t)(m0 + ar) * D_ + k0 + ak);
        float4 bv = *(const float4*)(W + (size_t)(k0 + bk) * H_ + n0 + bc);
        __syncthreads();
        sA[ak + 0][ar] = av.x; sA[ak + 1][ar] = av.y;
        sA[ak + 2][ar] = av.z; sA[ak + 3][ar] = av.w;
        *(float4*)&sB[bk][bc] = bv;
        __syncthreads();
#pragma unroll
        for (int kk = 0; kk < 16; ++kk) {
            float4 a = *(const float4*)&sA[kk][ty * 4];
            float4 b = *(const float4*)&sB[kk][tx * 4];
            acc[0][0] += a.x*b.x; acc[0][1] += a.x*b.y; acc[0][2] += a.x*b.z; acc[0][3] += a.x*b.w;
            acc[1][0] += a.y*b.x; acc[1][1] += a.y*b.y; acc[1][2] += a.y*b.z; acc[1][3] += a.y*b.w;
            acc[2][0] += a.z*b.x; acc[2][1] += a.z*b.y; acc[2][2] += a.z*b.z; acc[2][3] += a.z*b.w;
            acc[3][0] += a.w*b.x; acc[3][1] += a.w*b.y; acc[3][2] += a.w*b.z; acc[3][3] += a.w*b.w;
        }
    }
#pragma unroll
    for (int i = 0; i < 4; ++i) {
        const int row = m0 + ty * 4 + i;
        const int col = n0 + tx * 4;
        float4 bv = *(const float4*)(bias + col);
        float4 o;
        o.x = acc[i][0] + bv.x; o.y = acc[i][1] + bv.y;
        o.z = acc[i][2] + bv.z; o.w = acc[i][3] + bv.w;
        *(float4*)(out + (size_t)row * H_ + col) = o;
    }
}

// ---------------------------------------------------------------------------
// Persistent recurrence kernel.
// 128 WGs = 4 rowgroups (16 batch rows) x 32 colgroups (32 hidden cols).
// U slice (32 cols x 1024 k, bf16 hi+lo) lives in LDS for all 512 steps.
// Per step: z-tile via MFMA (hi/lo split) -> stats partials -> group barrier
//           -> LN+tanh on registers -> write out + h(hi/lo) -> group barrier.
// ---------------------------------------------------------------------------
#define UPAD 1032   // 1024 + 8 bf16 pad (16B) to break LDS bank conflicts

__device__ __forceinline__ void gbar(int* c, int n, int tid) {
    __syncthreads();
    if (tid == 0) {
        __threadfence();  // agent-scope release (flush L2 for cross-XCD readers)
        __hip_atomic_fetch_add(c, 1, __ATOMIC_ACQ_REL, __HIP_MEMORY_SCOPE_AGENT);
        while (__hip_atomic_load(c, __ATOMIC_ACQUIRE, __HIP_MEMORY_SCOPE_AGENT) < n)
            __builtin_amdgcn_s_sleep(1);
        __threadfence();  // agent-scope acquire
    }
    __syncthreads();
}

__global__ __launch_bounds__(256, 1) void rnn_kernel(
    const float* __restrict__ U, const float* __restrict__ gamma,
    const float* __restrict__ beta, float* __restrict__ out,
    int* __restrict__ cnt, unsigned short* __restrict__ hhi,
    unsigned short* __restrict__ hlo, float2* __restrict__ stats)
{
    extern __shared__ char smem[];
    unsigned short* Uhi = (unsigned short*)smem;            // [32][UPAD]
    unsigned short* Ulo = Uhi + 32 * UPAD;                  // [32][UPAD]
    float*  red  = (float*)(Ulo + 32 * UPAD);               // [2][64][4]
    float2* sred = (float2*)(red + 512);                    // [16][16]
    float*  smu  = (float*)(sred + 256);                    // [16]
    float*  srs  = smu + 16;                                // [16]

    const int wg  = blockIdx.x;
    const int rg  = wg >> 5;        // rowgroup 0..3 (16 batch rows)
    const int cg  = wg & 31;        // colgroup 0..31 (32 cols)
    const int tid = threadIdx.x;
    const int w   = tid >> 6;       // wave 0..3
    const int l   = tid & 63;
    const int ct  = w >> 1;         // col-tile 0/1 (16 cols)
    const int kh  = w & 1;          // k-half 0/1 (512 k)
    const int lc  = l & 15;         // A-row / B-col / C-col lane index
    const int lh  = l >> 4;         // k-subgroup / C-row group

    // ---- one-time: stage U[:, cg*32 .. +32] into LDS as bf16 hi/lo, [col][k]
    const int c0 = cg * 32;
    for (int kk = 0; kk < H_; kk += 32) {
        int k  = kk + (tid >> 3);
        int c4 = (tid & 7) * 4;
        float4 u = *(const float4*)(U + (size_t)k * H_ + c0 + c4);
        float uu[4] = {u.x, u.y, u.z, u.w};
#pragma unroll
        for (int e = 0; e < 4; ++e) {
            unsigned short hb = f32_to_bf16_rn(uu[e]);
            unsigned short lb = f32_to_bf16_rn(uu[e] - bf16_to_f32(hb));
            Uhi[(size_t)(c4 + e) * UPAD + k] = hb;
            Ulo[(size_t)(c4 + e) * UPAD + k] = lb;
        }
    }
    __syncthreads();

    const int col = c0 + ct * 16 + lc;                // this lane's output col (kh0)
    const float gmv = gamma[col];
    const float btv = beta[col];

    const unsigned short* ubh = Uhi + (size_t)(ct * 16 + lc) * UPAD + kh * 512;
    const unsigned short* ubl = Ulo + (size_t)(ct * 16 + lc) * UPAD + kh * 512;
    const unsigned short* hrh = hhi + (size_t)(rg * 16 + lc) * H_ + kh * 512;
    const unsigned short* hrl = hlo + (size_t)(rg * 16 + lc) * H_ + kh * 512;

    for (int t = 0; t < T_; ++t) {
        // ---- MM phase: z-tile partial (16 rows x 16 cols, this wave's k-half)
        f32x4 acc0 = {0.f,0.f,0.f,0.f}, acc1 = {0.f,0.f,0.f,0.f};
        f32x4 acc2 = {0.f,0.f,0.f,0.f}, acc3 = {0.f,0.f,0.f,0.f};
#pragma unroll
        for (int ks = 0; ks < 16; ++ks) {
            bf16x8 ah = *(const bf16x8*)(hrh + ks * 32 + lh * 8);
            bf16x8 al = *(const bf16x8*)(hrl + ks * 32 + lh * 8);
            bf16x8 bh = *(const bf16x8*)(ubh + ks * 32 + lh * 8);
            bf16x8 bl = *(const bf16x8*)(ubl + ks * 32 + lh * 8);
            f32x4 a = (ks & 2) ? ((ks & 1) ? acc3 : acc2) : ((ks & 1) ? acc1 : acc0);
            a = __builtin_amdgcn_mfma_f32_16x16x32_bf16(ah, bh, a, 0, 0, 0);
            a = __builtin_amdgcn_mfma_f32_16x16x32_bf16(ah, bl, a, 0, 0, 0);
            a = __builtin_amdgcn_mfma_f32_16x16x32_bf16(al, bh, a, 0, 0, 0);
            if (ks & 2) { if (ks & 1) acc3 = a; else acc2 = a; }
            else        { if (ks & 1) acc1 = a; else acc0 = a; }
        }
        f32x4 z4 = (acc0 + acc1) + (acc2 + acc3);

        // ---- cross-k reduce via LDS (kh1 -> kh0)
        if (kh == 1) *(f32x4*)(red + (size_t)(ct * 64 + l) * 4) = z4;
        __syncthreads();

        float zz[4];
        if (kh == 0) {
            z4 += *(const f32x4*)(red + (size_t)(ct * 64 + l) * 4);
            float s[4], q[4];
#pragma unroll
            for (int j = 0; j < 4; ++j) {
                int b = rg * 16 + lh * 4 + j;
                zz[j] = z4[j] + out[((size_t)b * T_ + t) * H_ + col];
                s[j] = zz[j];
                q[j] = zz[j] * zz[j];
            }
#pragma unroll
            for (int m = 1; m < 16; m <<= 1) {
#pragma unroll
                for (int j = 0; j < 4; ++j) {
                    s[j] += __shfl_xor(s[j], m);
                    q[j] += __shfl_xor(q[j], m);
                }
            }
            if (lc == 0) {
#pragma unroll
                for (int j = 0; j < 4; ++j)
                    stats[((size_t)rg * 64 + cg * 2 + ct) * 16 + lh * 4 + j] =
                        make_float2(s[j], q[j]);
            }
        }

        gbar(cnt + rg * 1024 + t * 2 + 0, 32, tid);

        // ---- LN stats finalize (all 64 partials for this rowgroup)
        {
            int r = tid & 15, seg = tid >> 4;
            float2 a = make_float2(0.f, 0.f);
#pragma unroll
            for (int e = 0; e < 4; ++e) {
                float2 v = stats[((size_t)rg * 64 + seg * 4 + e) * 16 + r];
                a.x += v.x; a.y += v.y;
            }
            sred[seg * 16 + r] = a;
        }
        __syncthreads();
        if (tid < 16) {
            float S = 0.f, Q = 0.f;
#pragma unroll
            for (int seg = 0; seg < 16; ++seg) {
                float2 v = sred[seg * 16 + tid];
                S += v.x; Q += v.y;
            }
            float mu  = S * (1.0f / H_);
            float var = Q * (1.0f / H_) - mu * mu;
            smu[tid] = mu;
            srs[tid] = rsqrtf(var + LN_EPS);
        }
        __syncthreads();

        // ---- apply LN + tanh, write out + h(hi/lo)
        if (kh == 0) {
#pragma unroll
            for (int j = 0; j < 4; ++j) {
                int r = lh * 4 + j;
                int b = rg * 16 + r;
                float o = tanhf((zz[j] - smu[r]) * srs[r] * gmv + btv);
                out[((size_t)b * T_ + t) * H_ + col] = o;
                unsigned short hb = f32_to_bf16_rn(o);
                unsigned short lb = f32_to_bf16_rn(o - bf16_to_f32(hb));
                hhi[(size_t)b * H_ + col] = hb;
                hlo[(size_t)b * H_ + col] = lb;
            }
        }

        gbar(cnt + rg * 1024 + t * 2 + 1, 32, tid);
    }
}

// ---------------------------------------------------------------------------
extern "C" void kernel_launch(void* const* d_in, const int* in_sizes, int n_in,
                              void* d_out, int out_size, void* d_ws, size_t ws_size,
                              hipStream_t stream)
{
    const float* X     = (const float*)d_in[0];
    const float* W     = (const float*)d_in[1];
    const float* U     = (const float*)d_in[2];
    const float* bias  = (const float*)d_in[3];
    const float* gamma = (const float*)d_in[4];
    const float* beta  = (const float*)d_in[5];
    float* out = (float*)d_out;

    // ws layout: [cnt 16KB][h_hi 128KB][h_lo 128KB][stats 32KB]
    int* cnt = (int*)d_ws;
    unsigned short* hhi = (unsigned short*)((char*)d_ws + 16384);
    unsigned short* hlo = hhi + (size_t)B_ * H_;
    float2* stats = (float2*)((char*)d_ws + 16384 + 2 * (size_t)B_ * H_ * 2);

    // zero counters + h state (ws is poisoned before every timed launch)
    hipMemsetAsync(d_ws, 0, 16384 + 2 * (size_t)B_ * H_ * 2, stream);

    gemm1_kernel<<<dim3(512, 16), 256, 0, stream>>>(X, W, bias, out);

    const int lds_bytes = 32 * UPAD * 2 * 2 + 512 * 4 + 256 * 8 + 32 * 4;
    hipFuncSetAttribute((const void*)rnn_kernel,
                        hipFuncAttributeMaxDynamicSharedMemorySize, lds_bytes);
    rnn_kernel<<<128, 256, lds_bytes, stream>>>(U, gamma, beta, out,
                                                cnt, hhi, hlo, stats);
}

// Round 3
// 7675.076 us; speedup vs baseline: 3.4971x; 1.6992x over previous
//
#include <hip/hip_runtime.h>
#include <hip/hip_bf16.h>

#define B_ 64
#define T_ 512
#define D_ 512
#define H_ 1024
#define LN_EPS 1e-3f

typedef short bf16x8 __attribute__((ext_vector_type(8)));
typedef float f32x4  __attribute__((ext_vector_type(4)));
typedef unsigned int u32x4 __attribute__((ext_vector_type(4)));

static __device__ __forceinline__ unsigned short f32_to_bf16_rn(float x) {
    unsigned u = __float_as_uint(x);
    unsigned r = (u + 0x7fffu + ((u >> 16) & 1u)) >> 16;
    return (unsigned short)r;
}
static __device__ __forceinline__ float bf16_to_f32(unsigned short h) {
    return __uint_as_float(((unsigned)h) << 16);
}

// ---------------------------------------------------------------------------
// GEMM1 (fp32 anchor): out = X@W + b   M=32768 K=512 N=1024  (~0.34 ms)
// ---------------------------------------------------------------------------
__global__ __launch_bounds__(256) void gemm1_kernel(
    const float* __restrict__ X, const float* __restrict__ W,
    const float* __restrict__ bias, float* __restrict__ out)
{
    __shared__ float sA[16][64];
    __shared__ float sB[16][64];
    const int m0 = blockIdx.x * 64;
    const int n0 = blockIdx.y * 64;
    const int t  = threadIdx.x;
    const int tx = t & 15, ty = t >> 4;
    const int ar = t >> 2, ak = (t & 3) * 4;
    const int bk = t >> 4, bc = (t & 15) * 4;

    float acc[4][4] = {};
    for (int k0 = 0; k0 < D_; k0 += 16) {
        float4 av = *(const float4*)(X + (size_t)(m0 + ar) * D_ + k0 + ak);
        float4 bv = *(const float4*)(W + (size_t)(k0 + bk) * H_ + n0 + bc);
        __syncthreads();
        sA[ak + 0][ar] = av.x; sA[ak + 1][ar] = av.y;
        sA[ak + 2][ar] = av.z; sA[ak + 3][ar] = av.w;
        *(float4*)&sB[bk][bc] = bv;
        __syncthreads();
#pragma unroll
        for (int kk = 0; kk < 16; ++kk) {
            float4 a = *(const float4*)&sA[kk][ty * 4];
            float4 b = *(const float4*)&sB[kk][tx * 4];
            acc[0][0] += a.x*b.x; acc[0][1] += a.x*b.y; acc[0][2] += a.x*b.z; acc[0][3] += a.x*b.w;
            acc[1][0] += a.y*b.x; acc[1][1] += a.y*b.y; acc[1][2] += a.y*b.z; acc[1][3] += a.y*b.w;
            acc[2][0] += a.z*b.x; acc[2][1] += a.z*b.y; acc[2][2] += a.z*b.z; acc[2][3] += a.z*b.w;
            acc[3][0] += a.w*b.x; acc[3][1] += a.w*b.y; acc[3][2] += a.w*b.z; acc[3][3] += a.w*b.w;
        }
    }
#pragma unroll
    for (int i = 0; i < 4; ++i) {
        const int row = m0 + ty * 4 + i;
        const int col = n0 + tx * 4;
        float4 bv = *(const float4*)(bias + col);
        float4 o;
        o.x = acc[i][0] + bv.x; o.y = acc[i][1] + bv.y;
        o.z = acc[i][2] + bv.z; o.w = acc[i][3] + bv.w;
        *(float4*)(out + (size_t)row * H_ + col) = o;
    }
}

// ---------------------------------------------------------------------------
// Persistent recurrence. 128 WGs = 4 rowgroups x 32 colgroups.
// Cross-WG data plane: write-through sc1 stores (relaxed AGENT atomics),
// plain cached reads after invalidate-only acquire fence. No buffer_wbl2.
// ---------------------------------------------------------------------------
#define UPAD 1032

__device__ __forceinline__ void gbar(int* c, int target, int tid) {
    // __syncthreads() drains each wave's vmcnt (writes at coherence point),
    // so the arrival add is a valid release without any L2 writeback.
    __syncthreads();
    if (tid == 0) {
        asm volatile("" ::: "memory");
        __hip_atomic_fetch_add(c, 1, __ATOMIC_RELAXED, __HIP_MEMORY_SCOPE_AGENT);
        while (__hip_atomic_load(c, __ATOMIC_RELAXED, __HIP_MEMORY_SCOPE_AGENT) < target) {}
        asm volatile("" ::: "memory");
    }
    __syncthreads();
    // invalidate-only acquire (buffer_inv): makes producers' sc1 stores
    // visible to our subsequent plain cached loads.
    __builtin_amdgcn_fence(__ATOMIC_ACQUIRE, "agent");
}

__global__ __launch_bounds__(256, 1) void rnn_kernel(
    const float* __restrict__ U, const float* __restrict__ gamma,
    const float* __restrict__ beta, float* __restrict__ out,
    int* __restrict__ cnt, unsigned int* __restrict__ hpk,
    unsigned long long* __restrict__ stats)
{
    extern __shared__ char smem[];
    unsigned short* Uhi = (unsigned short*)smem;            // [32][UPAD]
    unsigned short* Ulo = Uhi + 32 * UPAD;                  // [32][UPAD]
    float*  red  = (float*)(Ulo + 32 * UPAD);               // [2][64][4]
    float2* sred = (float2*)(red + 512);                    // [16][16]
    float*  smu  = (float*)(sred + 256);                    // [16]
    float*  srs  = smu + 16;                                // [16]

    const int wg  = blockIdx.x;
    const int rg  = wg >> 5;        // rowgroup (16 batch rows)
    const int cg  = wg & 31;        // colgroup (32 cols)
    const int tid = threadIdx.x;
    const int w   = tid >> 6;
    const int l   = tid & 63;
    const int ct  = w >> 1;         // col-tile 0/1
    const int kh  = w & 1;          // k-half 0/1
    const int lc  = l & 15;
    const int lh  = l >> 4;

    // ---- stage U[:, cg*32..+32] into LDS as bf16 hi/lo, [col][k]
    const int c0 = cg * 32;
    for (int kk = 0; kk < H_; kk += 32) {
        int k  = kk + (tid >> 3);
        int c4 = (tid & 7) * 4;
        float4 u = *(const float4*)(U + (size_t)k * H_ + c0 + c4);
        float uu[4] = {u.x, u.y, u.z, u.w};
#pragma unroll
        for (int e = 0; e < 4; ++e) {
            unsigned short hb = f32_to_bf16_rn(uu[e]);
            unsigned short lb = f32_to_bf16_rn(uu[e] - bf16_to_f32(hb));
            Uhi[(size_t)(c4 + e) * UPAD + k] = hb;
            Ulo[(size_t)(c4 + e) * UPAD + k] = lb;
        }
    }
    __syncthreads();

    const int col = c0 + ct * 16 + lc;
    const float gmv = gamma[col];
    const float btv = beta[col];

    const unsigned short* ubh = Uhi + (size_t)(ct * 16 + lc) * UPAD + kh * 512;
    const unsigned short* ubl = Ulo + (size_t)(ct * 16 + lc) * UPAD + kh * 512;
    const unsigned int*  hrow = hpk + (size_t)(rg * 16 + lc) * H_ + kh * 512;

    int* bar0 = cnt + (rg * 2 + 0) * 32;   // 128B-padded counters
    int* bar1 = cnt + (rg * 2 + 1) * 32;

    for (int t = 0; t < T_; ++t) {
        // ---- prefetch xW tile early (overlaps with MFMA + LDS reads)
        float xwv[4];
        if (kh == 0) {
#pragma unroll
            for (int j = 0; j < 4; ++j)
                xwv[j] = out[((size_t)(rg * 16 + lh * 4 + j) * T_ + t) * H_ + col];
        }

        // ---- MM: z-tile partial, hi/lo split (3 MFMAs per k-slice)
        f32x4 acc0 = {0.f,0.f,0.f,0.f}, acc1 = {0.f,0.f,0.f,0.f};
        f32x4 acc2 = {0.f,0.f,0.f,0.f}, acc3 = {0.f,0.f,0.f,0.f};
#pragma unroll
        for (int ks = 0; ks < 16; ++ks) {
            u32x4 p0 = *(const u32x4*)(hrow + ks * 32 + lh * 8);
            u32x4 p1 = *(const u32x4*)(hrow + ks * 32 + lh * 8 + 4);
            union { bf16x8 v; unsigned int u[4]; } ah, al;
            ah.u[0] = __builtin_amdgcn_perm(p0.y, p0.x, 0x07060302u);
            al.u[0] = __builtin_amdgcn_perm(p0.y, p0.x, 0x05040100u);
            ah.u[1] = __builtin_amdgcn_perm(p0.w, p0.z, 0x07060302u);
            al.u[1] = __builtin_amdgcn_perm(p0.w, p0.z, 0x05040100u);
            ah.u[2] = __builtin_amdgcn_perm(p1.y, p1.x, 0x07060302u);
            al.u[2] = __builtin_amdgcn_perm(p1.y, p1.x, 0x05040100u);
            ah.u[3] = __builtin_amdgcn_perm(p1.w, p1.z, 0x07060302u);
            al.u[3] = __builtin_amdgcn_perm(p1.w, p1.z, 0x05040100u);
            bf16x8 bh = *(const bf16x8*)(ubh + ks * 32 + lh * 8);
            bf16x8 bl = *(const bf16x8*)(ubl + ks * 32 + lh * 8);
            f32x4 a = (ks & 2) ? ((ks & 1) ? acc3 : acc2) : ((ks & 1) ? acc1 : acc0);
            a = __builtin_amdgcn_mfma_f32_16x16x32_bf16(ah.v, bh, a, 0, 0, 0);
            a = __builtin_amdgcn_mfma_f32_16x16x32_bf16(ah.v, bl, a, 0, 0, 0);
            a = __builtin_amdgcn_mfma_f32_16x16x32_bf16(al.v, bh, a, 0, 0, 0);
            if (ks & 2) { if (ks & 1) acc3 = a; else acc2 = a; }
            else        { if (ks & 1) acc1 = a; else acc0 = a; }
        }
        f32x4 z4 = (acc0 + acc1) + (acc2 + acc3);

        // ---- cross-k reduce (kh1 -> kh0) via LDS
        if (kh == 1) *(f32x4*)(red + (size_t)(ct * 64 + l) * 4) = z4;
        __syncthreads();

        float zz[4];
        if (kh == 0) {
            z4 += *(const f32x4*)(red + (size_t)(ct * 64 + l) * 4);
            float s_[4], q_[4];
#pragma unroll
            for (int j = 0; j < 4; ++j) {
                zz[j] = z4[j] + xwv[j];
                s_[j] = zz[j];
                q_[j] = zz[j] * zz[j];
            }
#pragma unroll
            for (int m = 1; m < 16; m <<= 1) {
#pragma unroll
                for (int j = 0; j < 4; ++j) {
                    s_[j] += __shfl_xor(s_[j], m);
                    q_[j] += __shfl_xor(q_[j], m);
                }
            }
            if (lc == 0) {
#pragma unroll
                for (int j = 0; j < 4; ++j) {
                    unsigned long long pk =
                        ((unsigned long long)__float_as_uint(q_[j]) << 32) |
                        (unsigned long long)__float_as_uint(s_[j]);
                    // write-through device-scope store (sc1)
                    __hip_atomic_store(
                        &stats[((size_t)rg * 16 + lh * 4 + j) * 64 + cg * 2 + ct],
                        pk, __ATOMIC_RELAXED, __HIP_MEMORY_SCOPE_AGENT);
                }
            }
        }

        gbar(bar0, 32 * (t + 1), tid);

        // ---- LN stats finalize: row r sums 64 partials ([rg][row][entry])
        {
            int r = tid & 15, seg = tid >> 4;
            const unsigned long long* sp =
                stats + ((size_t)rg * 16 + r) * 64 + seg * 4;
            float S = 0.f, Q = 0.f;
#pragma unroll
            for (int e = 0; e < 4; ++e) {
                unsigned long long v = sp[e];
                S += __uint_as_float((unsigned)v);
                Q += __uint_as_float((unsigned)(v >> 32));
            }
            sred[seg * 16 + r] = make_float2(S, Q);
        }
        __syncthreads();
        if (tid < 16) {
            float S = 0.f, Q = 0.f;
#pragma unroll
            for (int seg = 0; seg < 16; ++seg) {
                float2 v = sred[seg * 16 + tid];
                S += v.x; Q += v.y;
            }
            float mu  = S * (1.0f / H_);
            float var = Q * (1.0f / H_) - mu * mu;
            smu[tid] = mu;
            srs[tid] = rsqrtf(var + LN_EPS);
        }
        __syncthreads();

        // ---- apply LN + tanh; write out (plain) + h packed hi|lo (sc1)
        if (kh == 0) {
#pragma unroll
            for (int j = 0; j < 4; ++j) {
                int r = lh * 4 + j;
                int b = rg * 16 + r;
                float o = tanhf((zz[j] - smu[r]) * srs[r] * gmv + btv);
                out[((size_t)b * T_ + t) * H_ + col] = o;
                unsigned short hb = f32_to_bf16_rn(o);
                unsigned short lb = f32_to_bf16_rn(o - bf16_to_f32(hb));
                __hip_atomic_store(&hpk[(size_t)b * H_ + col],
                                   (((unsigned)hb) << 16) | (unsigned)lb,
                                   __ATOMIC_RELAXED, __HIP_MEMORY_SCOPE_AGENT);
            }
        }

        if (t < T_ - 1) gbar(bar1, 32 * (t + 1), tid);
    }
}

// ---------------------------------------------------------------------------
extern "C" void kernel_launch(void* const* d_in, const int* in_sizes, int n_in,
                              void* d_out, int out_size, void* d_ws, size_t ws_size,
                              hipStream_t stream)
{
    const float* X     = (const float*)d_in[0];
    const float* W     = (const float*)d_in[1];
    const float* U     = (const float*)d_in[2];
    const float* bias  = (const float*)d_in[3];
    const float* gamma = (const float*)d_in[4];
    const float* beta  = (const float*)d_in[5];
    float* out = (float*)d_out;

    // ws: [cnt 1KB (8 counters, 128B apart)][hpk 256KB][stats 32KB]
    int* cnt = (int*)d_ws;
    unsigned int* hpk = (unsigned int*)((char*)d_ws + 1024);
    unsigned long long* stats =
        (unsigned long long*)((char*)d_ws + 1024 + (size_t)B_ * H_ * 4);

    // zero counters + h state
    hipMemsetAsync(d_ws, 0, 1024 + (size_t)B_ * H_ * 4, stream);

    gemm1_kernel<<<dim3(512, 16), 256, 0, stream>>>(X, W, bias, out);

    const int lds_bytes = 32 * UPAD * 2 * 2 + 512 * 4 + 256 * 8 + 32 * 4;
    hipFuncSetAttribute((const void*)rnn_kernel,
                        hipFuncAttributeMaxDynamicSharedMemorySize, lds_bytes);
    rnn_kernel<<<128, 256, lds_bytes, stream>>>(U, gamma, beta, out,
                                                cnt, hpk, stats);
}